// Round 5
// baseline (532.554 us; speedup 1.0000x reference)
//
#include <hip/hip_runtime.h>
#include <hip/hip_bf16.h>

// ---------------- problem constants ----------------
constexpr int T  = 16384;   // B*S tokens
constexpr int Dh = 768;
constexpr int Fh = 3072;
constexpr int Eh = 8;
constexpr int MAXT2 = T / 256 + Eh;   // 72 tiles max at 256-row granularity

typedef unsigned short ushort_t;
typedef __attribute__((ext_vector_type(8))) short  bf16x8;  // 8 bf16 = 4 VGPRs
typedef __attribute__((ext_vector_type(4))) float  f32x4;

// fp32 -> bf16 round-to-nearest-even (finite inputs)
static __device__ __forceinline__ ushort_t f2bf(float f) {
    unsigned u = __builtin_bit_cast(unsigned, f);
    u += 0x7FFFu + ((u >> 16) & 1u);
    return (ushort_t)(u >> 16);
}

// ---------------- router v2: 16 tokens per 1024-thread block ----------------
__global__ __launch_bounds__(1024) void router_kernel(
    const float* __restrict__ x, const float* __restrict__ rw,
    float* __restrict__ logits_out, float* __restrict__ eidx_out,
    float* __restrict__ topp, int* __restrict__ counts, int* __restrict__ perm) {

    __shared__ float rwT[Eh][Dh];   // 24 KB, transposed router weights
    __shared__ int   sAmax[16];
    __shared__ int   sBase[Eh];

    int tid = threadIdx.x;
    for (int i = tid; i < Dh * Eh; i += 1024) {
        int d = i >> 3, e = i & 7;
        rwT[e][d] = rw[i];
    }
    __syncthreads();

    int wave = tid >> 6, lane = tid & 63;
    int t = blockIdx.x * 16 + wave;
    const float* xr = x + (size_t)t * Dh;

    double acc[Eh];
#pragma unroll
    for (int e = 0; e < Eh; ++e) acc[e] = 0.0;

#pragma unroll
    for (int j = 0; j < Dh / 256; ++j) {
        int d = lane * 4 + j * 256;
        const float4 xv = *(const float4*)(xr + d);
#pragma unroll
        for (int e = 0; e < Eh; ++e) {
            const float4 w = *(const float4*)&rwT[e][d];
            acc[e] += (double)xv.x * (double)w.x + (double)xv.y * (double)w.y
                    + (double)xv.z * (double)w.z + (double)xv.w * (double)w.w;
        }
    }
#pragma unroll
    for (int off = 32; off > 0; off >>= 1) {
#pragma unroll
        for (int e = 0; e < Eh; ++e) acc[e] += __shfl_xor(acc[e], off, 64);
    }

    int amax = 0;
    if (lane == 0) {
        float l32[Eh];
        float m = -3.4e38f;
#pragma unroll
        for (int e = 0; e < Eh; ++e) l32[e] = (float)acc[e];
#pragma unroll
        for (int e = 0; e < Eh; ++e) {
            if (l32[e] > m) { m = l32[e]; amax = e; }  // strict > : first max wins
        }
        float s = 0.f;
#pragma unroll
        for (int e = 0; e < Eh; ++e) s += expf(l32[e] - m);
#pragma unroll
        for (int e = 0; e < Eh; ++e) logits_out[(size_t)t * Eh + e] = l32[e];
        eidx_out[t] = (float)amax;
        topp[t]     = 1.0f / s;
        sAmax[wave] = amax;
    }
    __syncthreads();

    if (tid < Eh) {
        int c = 0;
#pragma unroll
        for (int w = 0; w < 16; ++w) c += (sAmax[w] == tid);
        sBase[tid] = (c > 0) ? atomicAdd(&counts[tid], c) : 0;
    }
    __syncthreads();

    if (lane == 0) {
        int prior = 0;
        for (int w = 0; w < wave; ++w) prior += (sAmax[w] == amax);
        perm[amax * T + sBase[amax] + prior] = t;
    }
}

// ---------------- scan counts + build tile list: parallel over 8 lanes ----------------
__global__ void scan_counts(const int* counts, int* offsets,
                            int* tE, int* tGoff, int* tSlot0, int* tRows, int* nT) {
    int lane = threadIdx.x;
    if (lane < Eh) {
        int coff = 0, toff = 0;
        for (int e = 0; e < lane; ++e) {
            int ce = counts[e];
            coff += ce;
            toff += (ce + 255) >> 8;
        }
        int c = counts[lane];
        offsets[lane] = coff;
        int myt = (c + 255) >> 8;
        for (int k = 0; k < myt; ++k) {
            int idx = toff + k;
            tE[idx]     = lane;
            tGoff[idx]  = coff + k * 256;
            tSlot0[idx] = k * 256;
            int rem = c - k * 256;
            tRows[idx]  = rem < 256 ? rem : 256;
        }
        if (lane == Eh - 1) {
            offsets[Eh] = coff + c;
            nT[0] = toff + myt;
        }
    }
}

// ---------------- gather tokens into expert-sorted bf16 rows ----------------
__global__ void gather_cast_x(const float* __restrict__ x, const int* __restrict__ offsets,
                              const int* __restrict__ perm, ushort_t* __restrict__ Xg) {
    __shared__ int soff[Eh + 1];
    if (threadIdx.x < Eh + 1) soff[threadIdx.x] = offsets[threadIdx.x];
    __syncthreads();
    int q  = blockIdx.x * 256 + threadIdx.x;     // float4 index, exact grid
    int g  = q / (Dh / 4);
    int cq = (q - g * (Dh / 4)) * 4;
    int e = 0;
#pragma unroll
    for (int i = 1; i < Eh; ++i) e += (g >= soff[i]);
    int tok = perm[e * T + (g - soff[e])];
    const float4 v = *(const float4*)(x + (size_t)tok * Dh + cq);
    ushort4 o;
    o.x = f2bf(v.x); o.y = f2bf(v.y); o.z = f2bf(v.z); o.w = f2bf(v.w);
    *(ushort4*)(Xg + (size_t)g * Dh + cq) = o;
}

// ---------------- transpose + cast v2: 64x64 tiles, float4 reads, ushort4 writes ----------
// src[R][C] fp32 -> dst[C][R] bf16. R, C divisible by 64.
__global__ __launch_bounds__(256) void transpose_cvt(
    const float* __restrict__ src, ushort_t* __restrict__ dst, int R, int C) {
    __shared__ ushort_t tile[64][65];
    int tid = threadIdx.x;
    size_t base = (size_t)blockIdx.z * (size_t)R * (size_t)C;
    int c0 = blockIdx.x * 64, r0 = blockIdx.y * 64;
    int rr  = tid >> 4;          // 0..15
    int cc4 = (tid & 15) * 4;    // float4 column within tile
#pragma unroll
    for (int p = 0; p < 4; ++p) {
        int r = rr + p * 16;
        const float4 v = *(const float4*)(src + base + (size_t)(r0 + r) * C + c0 + cc4);
        tile[r][cc4 + 0] = f2bf(v.x);
        tile[r][cc4 + 1] = f2bf(v.y);
        tile[r][cc4 + 2] = f2bf(v.z);
        tile[r][cc4 + 3] = f2bf(v.w);
    }
    __syncthreads();
    int co = tid >> 4;           // output col (src col) per pass
    int rp = (tid & 15) * 4;     // quad of src rows
#pragma unroll
    for (int p = 0; p < 4; ++p) {
        int c = co + p * 16;
        ushort4 o = { tile[rp][c], tile[rp + 1][c], tile[rp + 2][c], tile[rp + 3][c] };
        *(ushort4*)(dst + base + (size_t)(c0 + c) * R + r0 + rp) = o;
    }
}

// ---------------- grouped GEMM v7: 256x256 tile, BK=32, 4-slot depth-3 pipeline --------
// A: [slot][KTOT] bf16 (expert-sorted rows). B: [E][NTOT][KTOT] bf16.
// THEORY (r5): staging was concurrency-bound (1 block/CU, ~6 loads in flight/wave).
// Fix: BK=32, 4 LDS slots (4 x 32 KB), prefetch depth 3 -> 12 loads in flight per wave
// sustained, tile t issued at iter t-3 (~4000 cyc of latency cover).
// Pipeline (ONE barrier per K-tile):
//   iter t entry barrier guarantees: (a) all waves' reads of tile t-1 done,
//     (b) per-wave vmcnt gate for tile t passed by everyone.
//   STAGE(t+3 -> slot (t+3)&3 == slot (t-1)&3)   // safe by (a), after barrier
//   READ 12 frags from slot t&3 (safe by (b)); 32 MFMA
//   vmcnt gate for t+1: steady vmcnt(8) (FIFO: oldest 4 = tile t+1 retired);
//     t=nkt-3 -> vmcnt(4); t=nkt-2 -> vmcnt(0); then barrier.
// LDS XOR-swizzle (4 chunks/row): chunk g of row r stored at g ^ (r&3); linear
// global_load_lds dest (byte off = c_*16, lane-linear), pre-swizzled global source.
// 2D XCD patch map: XCD x owns row-tiles [9x, 9x+9) for ALL ytiles, y-major order,
// so A-tiles and B-panels are re-read from the same XCD's L2.
// MODE 0: h = relu(A*B^T) -> bf16, rows = global slot. MODE 1: out = prob*(A*B^T) -> fp32.
template<int KTOT, int NTOT, int MODE>
__global__ __launch_bounds__(512, 2) void moe_gemm2(
    const ushort_t* __restrict__ Aall, const ushort_t* __restrict__ Ball,
    const int* __restrict__ tE, const int* __restrict__ tGoff,
    const int* __restrict__ tSlot0, const int* __restrict__ tRows,
    const int* __restrict__ nT,
    const int* __restrict__ perm, const float* __restrict__ topp,
    void* __restrict__ Cout)
{
    // ---- 2D XCD patch mapping: grid = MAXT2 * NY, MAXT2 = 72 = 8 XCDs x 9 ----
    int xcd = blockIdx.x & 7;
    int pos = blockIdx.x >> 3;             // [0, 9*NY)
    int ytile = pos / 9;                   // y-major within the XCD chunk
    int i     = xcd * 9 + (pos - ytile * 9);

    if (i >= nT[0]) return;
    int e     = tE[i];
    int goff  = tGoff[i];
    int slot0 = tSlot0[i];
    int rows  = tRows[i];
    int n0    = ytile * 256;

    const ushort_t* Ap = Aall + (size_t)goff * KTOT;
    const ushort_t* Bp = Ball + (size_t)e * KTOT * NTOT + (size_t)n0 * KTOT;

    __shared__ ushort_t As[4][256 * 32];   // 4 x 16 KB
    __shared__ ushort_t Bs[4][256 * 32];   // 4 x 16 KB
    __shared__ int   tokLds[256];
    __shared__ float probLds[256];

    int tid = threadIdx.x, lane = tid & 63, wid_w = tid >> 6;
    int wr = wid_w >> 2, wc = wid_w & 3;   // wave owns rows wr*128..+128, cols wc*64..+64
    int gq = lane >> 4, lm = lane & 15;
    int lm3 = lm & 3;

    if (MODE == 1 && tid < 256) {
        int tok = (tid < rows) ? perm[e * T + slot0 + tid] : 0;
        tokLds[tid]  = tok;
        probLds[tid] = (tid < rows) ? topp[tok] : 0.f;
    }

    f32x4 acc[8][4];                       // [mi 16-row frag][ni 16-col frag]
    const f32x4 zero = {0.f, 0.f, 0.f, 0.f};
#pragma unroll
    for (int mi = 0; mi < 8; ++mi)
#pragma unroll
        for (int ni = 0; ni < 4; ++ni) acc[mi][ni] = zero;

    // ---- staging: one 256x32 K-slab of A and B = 2+2 x 16B loads/thread ----
    // c_ in [0,1024): rr = c_>>2 row, gg = c_&3 chunk. LDS byte off = c_*16
    // (lane-linear, wave-uniform base ✓). Source chunk pre-swizzled: gg ^ (rr&3).
#define STAGE(SLOT, KT) { \
    _Pragma("unroll") \
    for (int j = 0; j < 2; ++j) { \
        int c_ = tid + j * 512; \
        int rr = c_ >> 2, gg = c_ & 3; \
        int srow_ = rr < rows ? rr : rows - 1; \
        const ushort_t* srcA_ = Ap + (size_t)srow_ * KTOT + (size_t)(KT) * 32 + ((gg ^ (rr & 3)) << 3); \
        __builtin_amdgcn_global_load_lds( \
            (const __attribute__((address_space(1))) unsigned int*)srcA_, \
            (__attribute__((address_space(3))) unsigned int*)&As[SLOT][c_ * 8], 16, 0, 0); \
    } \
    _Pragma("unroll") \
    for (int j = 0; j < 2; ++j) { \
        int c_ = tid + j * 512; \
        int rr = c_ >> 2, gg = c_ & 3; \
        const ushort_t* srcB_ = Bp + (size_t)rr * KTOT + (size_t)(KT) * 32 + ((gg ^ (rr & 3)) << 3); \
        __builtin_amdgcn_global_load_lds( \
            (const __attribute__((address_space(1))) unsigned int*)srcB_, \
            (__attribute__((address_space(3))) unsigned int*)&Bs[SLOT][c_ * 8], 16, 0, 0); \
    } }

    const int nkt = KTOT / 32;             // 24 (GEMM1) / 96 (GEMM2), both >= 4

    // ---- prologue: stage tiles 0,1,2; gate tile 0 (12 outstanding -> keep 8) ----
    STAGE(0, 0);
    STAGE(1, 1);
    STAGE(2, 2);
    asm volatile("s_waitcnt vmcnt(8)" ::: "memory");
    __builtin_amdgcn_sched_barrier(0);
    __builtin_amdgcn_s_barrier();

    for (int t = 0; t < nkt; ++t) {
        const int SL = t & 3;
        if (t + 3 < nkt) STAGE((t + 3) & 3, t + 3);

        // ---- read all 12 fragments of tile t (compiler pipelines lgkm waits) ----
        bf16x8 af[8], bb[4];
#pragma unroll
        for (int ni = 0; ni < 4; ++ni)
            bb[ni] = *(const bf16x8*)&Bs[SL][(wc * 64 + ni * 16 + lm) * 32 + ((gq ^ lm3) << 3)];
#pragma unroll
        for (int mi = 0; mi < 8; ++mi)
            af[mi] = *(const bf16x8*)&As[SL][(wr * 128 + mi * 16 + lm) * 32 + ((gq ^ lm3) << 3)];

        __builtin_amdgcn_s_setprio(1);
#pragma unroll
        for (int mi = 0; mi < 8; ++mi)
#pragma unroll
            for (int ni = 0; ni < 4; ++ni)
                acc[mi][ni] = __builtin_amdgcn_mfma_f32_16x16x32_bf16(
                    af[mi], bb[ni], acc[mi][ni], 0, 0, 0);
        __builtin_amdgcn_s_setprio(0);

        // ---- per-wave gate for tile t+1, then all-wave barrier ----
        if (t + 1 < nkt) {
            if (t + 3 < nkt) {
                asm volatile("s_waitcnt vmcnt(8)" ::: "memory");   // t+1 retired (FIFO)
            } else if (t + 2 < nkt) {
                asm volatile("s_waitcnt vmcnt(4)" ::: "memory");   // only t+2 outstanding
            } else {
                asm volatile("s_waitcnt vmcnt(0)" ::: "memory");   // tail
            }
            __builtin_amdgcn_sched_barrier(0);
        }
        __builtin_amdgcn_s_barrier();
    }

    // ---- epilogue: C layout col = lane&15, row = (lane>>4)*4 + reg ----
    int cr = (lane >> 4) * 4;
    int cc = lane & 15;
#pragma unroll
    for (int mi = 0; mi < 8; ++mi) {
#pragma unroll
        for (int r = 0; r < 4; ++r) {
            int m = wr * 128 + mi * 16 + cr + r;
            if (m < rows) {
                if (MODE == 0) {
                    ushort_t* hp = (ushort_t*)Cout + (size_t)(goff + m) * NTOT
                                 + n0 + wc * 64 + cc;
#pragma unroll
                    for (int ni = 0; ni < 4; ++ni) {
                        float v = acc[mi][ni][r];
                        hp[ni * 16] = f2bf(v > 0.f ? v : 0.f);
                    }
                } else {
                    int tok = tokLds[m];
                    float p = probLds[m];
                    float* op = (float*)Cout + (size_t)tok * NTOT
                              + n0 + wc * 64 + cc;
#pragma unroll
                    for (int ni = 0; ni < 4; ++ni) op[ni * 16] = acc[mi][ni][r] * p;
                }
            }
        }
    }
#undef STAGE
}

// ---------------- workspace layout (unchanged) ----------------
constexpr size_t OFF_COUNTS  = 0;
constexpr size_t OFF_OFFSETS = 256;
constexpr size_t OFF_TILES   = 512;                                      // 5 arrays of 144 ints + nT
constexpr size_t OFF_TOPP    = OFF_TILES + 4 * 144 * 5 + 64;
constexpr size_t OFF_PERM    = OFF_TOPP + (size_t)T * 4;
constexpr size_t OFF_XG      = (OFF_PERM + (size_t)Eh * T * 4 + 255) & ~(size_t)255;
constexpr size_t OFF_H       = (OFF_XG + (size_t)(T + 128) * Dh * 2 + 255) & ~(size_t)255;
constexpr size_t OFF_WIN     = (OFF_H + (size_t)(T + 128) * Fh * 2 + 255) & ~(size_t)255;
constexpr size_t OFF_WOUT    = (OFF_WIN + (size_t)Eh * Dh * Fh * 2 + 255) & ~(size_t)255;

extern "C" void kernel_launch(void* const* d_in, const int* in_sizes, int n_in,
                              void* d_out, int out_size, void* d_ws, size_t ws_size,
                              hipStream_t stream) {
    const float* x    = (const float*)d_in[0];   // [T, Dh]
    const float* rw   = (const float*)d_in[1];   // [Dh, Eh]
    const float* w_in = (const float*)d_in[2];   // [Eh, Dh, Fh]
    const float* w_out= (const float*)d_in[3];   // [Eh, Fh, Dh]

    float* out    = (float*)d_out;               // [T, Dh]
    float* logits = out + (size_t)T * Dh;        // [T, Eh]
    float* eidx   = logits + (size_t)T * Eh;     // [T] (stored as float)

    char* ws = (char*)d_ws;
    int*      counts  = (int*)(ws + OFF_COUNTS);
    int*      offsets = (int*)(ws + OFF_OFFSETS);
    int*      tE      = (int*)(ws + OFF_TILES);
    int*      tGoff   = tE + 144;
    int*      tSlot0  = tGoff + 144;
    int*      tRows   = tSlot0 + 144;
    int*      nT      = tRows + 144;
    float*    topp    = (float*)(ws + OFF_TOPP);
    int*      perm    = (int*)(ws + OFF_PERM);
    ushort_t* Xg      = (ushort_t*)(ws + OFF_XG);
    ushort_t* h       = (ushort_t*)(ws + OFF_H);
    ushort_t* WinT    = (ushort_t*)(ws + OFF_WIN);   // [E][Fh][Dh]
    ushort_t* WoutT   = (ushort_t*)(ws + OFF_WOUT);  // [E][Dh][Fh]

    hipMemsetAsync(counts, 0, Eh * sizeof(int), stream);
    router_kernel<<<T / 16, 1024, 0, stream>>>(x, rw, logits, eidx, topp, counts, perm);
    scan_counts<<<1, 64, 0, stream>>>(counts, offsets, tE, tGoff, tSlot0, tRows, nT);
    gather_cast_x<<<(T * (Dh / 4)) / 256, 256, 0, stream>>>(x, offsets, perm, Xg);
    transpose_cvt<<<dim3(Fh / 64, Dh / 64, Eh), 256, 0, stream>>>(w_in, WinT, Dh, Fh);
    transpose_cvt<<<dim3(Dh / 64, Fh / 64, Eh), 256, 0, stream>>>(w_out, WoutT, Fh, Dh);
    moe_gemm2<Dh, Fh, 0><<<dim3(MAXT2 * (Fh / 256)), 512, 0, stream>>>(
        Xg, WinT, tE, tGoff, tSlot0, tRows, nT, perm, topp, (void*)h);
    moe_gemm2<Fh, Dh, 1><<<dim3(MAXT2 * (Dh / 256)), 512, 0, stream>>>(
        h, WoutT, tE, tGoff, tSlot0, tRows, nT, perm, topp, (void*)out);
}

// Round 6
// 470.974 us; speedup vs baseline: 1.1308x; 1.1308x over previous
//
#include <hip/hip_runtime.h>
#include <hip/hip_bf16.h>

// ---------------- problem constants ----------------
constexpr int T  = 16384;   // B*S tokens
constexpr int Dh = 768;
constexpr int Fh = 3072;
constexpr int Eh = 8;
constexpr int ROWT = T / 128 + Eh;    // 136 = 8 XCDs x 17 row-tiles at 128-row granularity

typedef unsigned short ushort_t;
typedef __attribute__((ext_vector_type(8))) short  bf16x8;  // 8 bf16 = 4 VGPRs
typedef __attribute__((ext_vector_type(4))) float  f32x4;

// fp32 -> bf16 round-to-nearest-even (finite inputs)
static __device__ __forceinline__ ushort_t f2bf(float f) {
    unsigned u = __builtin_bit_cast(unsigned, f);
    u += 0x7FFFu + ((u >> 16) & 1u);
    return (ushort_t)(u >> 16);
}

// ---------------- router v2: 16 tokens per 1024-thread block ----------------
__global__ __launch_bounds__(1024) void router_kernel(
    const float* __restrict__ x, const float* __restrict__ rw,
    float* __restrict__ logits_out, float* __restrict__ eidx_out,
    float* __restrict__ topp, int* __restrict__ counts, int* __restrict__ perm) {

    __shared__ float rwT[Eh][Dh];   // 24 KB, transposed router weights
    __shared__ int   sAmax[16];
    __shared__ int   sBase[Eh];

    int tid = threadIdx.x;
    for (int i = tid; i < Dh * Eh; i += 1024) {
        int d = i >> 3, e = i & 7;
        rwT[e][d] = rw[i];
    }
    __syncthreads();

    int wave = tid >> 6, lane = tid & 63;
    int t = blockIdx.x * 16 + wave;
    const float* xr = x + (size_t)t * Dh;

    double acc[Eh];
#pragma unroll
    for (int e = 0; e < Eh; ++e) acc[e] = 0.0;

#pragma unroll
    for (int j = 0; j < Dh / 256; ++j) {
        int d = lane * 4 + j * 256;
        const float4 xv = *(const float4*)(xr + d);
#pragma unroll
        for (int e = 0; e < Eh; ++e) {
            const float4 w = *(const float4*)&rwT[e][d];
            acc[e] += (double)xv.x * (double)w.x + (double)xv.y * (double)w.y
                    + (double)xv.z * (double)w.z + (double)xv.w * (double)w.w;
        }
    }
#pragma unroll
    for (int off = 32; off > 0; off >>= 1) {
#pragma unroll
        for (int e = 0; e < Eh; ++e) acc[e] += __shfl_xor(acc[e], off, 64);
    }

    int amax = 0;
    if (lane == 0) {
        float l32[Eh];
        float m = -3.4e38f;
#pragma unroll
        for (int e = 0; e < Eh; ++e) l32[e] = (float)acc[e];
#pragma unroll
        for (int e = 0; e < Eh; ++e) {
            if (l32[e] > m) { m = l32[e]; amax = e; }  // strict > : first max wins
        }
        float s = 0.f;
#pragma unroll
        for (int e = 0; e < Eh; ++e) s += expf(l32[e] - m);
#pragma unroll
        for (int e = 0; e < Eh; ++e) logits_out[(size_t)t * Eh + e] = l32[e];
        eidx_out[t] = (float)amax;
        topp[t]     = 1.0f / s;
        sAmax[wave] = amax;
    }
    __syncthreads();

    if (tid < Eh) {
        int c = 0;
#pragma unroll
        for (int w = 0; w < 16; ++w) c += (sAmax[w] == tid);
        sBase[tid] = (c > 0) ? atomicAdd(&counts[tid], c) : 0;
    }
    __syncthreads();

    if (lane == 0) {
        int prior = 0;
        for (int w = 0; w < wave; ++w) prior += (sAmax[w] == amax);
        perm[amax * T + sBase[amax] + prior] = t;
    }
}

// ---------------- scan counts + build tile list (128-row granularity) ----------------
// Arrays stride 160 ints: tE, tGoff, tSlot0, tRows; nT at +640.
__global__ void scan_counts(const int* counts, int* offsets, int* L) {
    int lane = threadIdx.x;
    if (lane < Eh) {
        int coff = 0, toff = 0;
        for (int e = 0; e < lane; ++e) {
            int ce = counts[e];
            coff += ce;
            toff += (ce + 127) >> 7;
        }
        int c = counts[lane];
        offsets[lane] = coff;
        int myt = (c + 127) >> 7;
        for (int k = 0; k < myt; ++k) {
            int idx = toff + k;
            L[idx]       = lane;            // tE
            L[160 + idx] = coff + k * 128;  // tGoff
            L[320 + idx] = k * 128;         // tSlot0
            int rem = c - k * 128;
            L[480 + idx] = rem < 128 ? rem : 128;  // tRows
        }
        if (lane == Eh - 1) {
            offsets[Eh] = coff + c;
            L[640] = toff + myt;            // nT
        }
    }
}

// ---------------- gather tokens into expert-sorted bf16 rows ----------------
__global__ void gather_cast_x(const float* __restrict__ x, const int* __restrict__ offsets,
                              const int* __restrict__ perm, ushort_t* __restrict__ Xg) {
    __shared__ int soff[Eh + 1];
    if (threadIdx.x < Eh + 1) soff[threadIdx.x] = offsets[threadIdx.x];
    __syncthreads();
    int q  = blockIdx.x * 256 + threadIdx.x;     // float4 index, exact grid
    int g  = q / (Dh / 4);
    int cq = (q - g * (Dh / 4)) * 4;
    int e = 0;
#pragma unroll
    for (int i = 1; i < Eh; ++i) e += (g >= soff[i]);
    int tok = perm[e * T + (g - soff[e])];
    const float4 v = *(const float4*)(x + (size_t)tok * Dh + cq);
    ushort4 o;
    o.x = f2bf(v.x); o.y = f2bf(v.y); o.z = f2bf(v.z); o.w = f2bf(v.w);
    *(ushort4*)(Xg + (size_t)g * Dh + cq) = o;
}

// ---------------- transpose + cast v2: 64x64 tiles, float4 reads, ushort4 writes ----------
__global__ __launch_bounds__(256) void transpose_cvt(
    const float* __restrict__ src, ushort_t* __restrict__ dst, int R, int C) {
    __shared__ ushort_t tile[64][65];
    int tid = threadIdx.x;
    size_t base = (size_t)blockIdx.z * (size_t)R * (size_t)C;
    int c0 = blockIdx.x * 64, r0 = blockIdx.y * 64;
    int rr  = tid >> 4;          // 0..15
    int cc4 = (tid & 15) * 4;    // float4 column within tile
#pragma unroll
    for (int p = 0; p < 4; ++p) {
        int r = rr + p * 16;
        const float4 v = *(const float4*)(src + base + (size_t)(r0 + r) * C + c0 + cc4);
        tile[r][cc4 + 0] = f2bf(v.x);
        tile[r][cc4 + 1] = f2bf(v.y);
        tile[r][cc4 + 2] = f2bf(v.z);
        tile[r][cc4 + 3] = f2bf(v.w);
    }
    __syncthreads();
    int co = tid >> 4;           // output col (src col) per pass
    int rp = (tid & 15) * 4;     // quad of src rows
#pragma unroll
    for (int p = 0; p < 4; ++p) {
        int c = co + p * 16;
        ushort4 o = { tile[rp][c], tile[rp + 1][c], tile[rp + 2][c], tile[rp + 3][c] };
        *(ushort4*)(dst + base + (size_t)(c0 + c) * R + r0 + rp) = o;
    }
}

// ---------------- grouped GEMM v8: 128x256 tile, 2 blocks/CU, cross-block overlap -------
// THEORY (r6): 256^2 kernels are 1 block/CU (acc=128 + ~128 VGPR = ~256 unified regs/wave
// -> 2 waves/SIMD). With one barrier-locked block, stage-writes / ds_reads / MFMA
// serialize (~6850 cyc/K-tile floor seen in R1-R5). Fix: acc=64 per wave (64x64 wave
// tile) -> ~120 VGPR -> 4 waves/SIMD -> TWO independent blocks/CU. Single-buffered LDS,
// trivial {stage; vmcnt(0); barrier; read+MFMA; barrier} loop; the co-resident block's
// compute overlaps this block's stage/drain (R0 evidence: multi-block staging hit
// 8.1 TB/s vs 4.6 for 1-block).
// A: [slot][KTOT] bf16 (expert-sorted rows). B: [E][NTOT][KTOT] bf16.
// LDS XOR-swizzle (proven 0-conflict): 16-B chunk g of row r holds source chunk g^(r&7);
// linear global_load_lds dest, pre-swizzled global source, swizzled ds_read.
// XCD map: grid = 136*NY, 136 = 8x17; xcd = b&7 owns row-tiles [17x,17x+17) for ALL
// ytiles, y-major -> per-XCD A-set L2-resident across ytiles (GEMM1: 3.3 MB).
// MODE 0: h = relu(A*B^T) -> bf16, rows = global slot. MODE 1: out = prob*(A*B^T) -> fp32.
template<int KTOT, int NTOT, int MODE>
__global__ __launch_bounds__(512, 4) void moe_gemm3(
    const ushort_t* __restrict__ Aall, const ushort_t* __restrict__ Ball,
    const int* __restrict__ tE, const int* __restrict__ tGoff,
    const int* __restrict__ tSlot0, const int* __restrict__ tRows,
    const int* __restrict__ nT,
    const int* __restrict__ perm, const float* __restrict__ topp,
    void* __restrict__ Cout)
{
    // ---- XCD-chunked map: b -> (row-tile i, ytile), y-major within each XCD chunk ----
    int b   = blockIdx.x;
    int xcd = b & 7;
    int pos = b >> 3;                      // [0, 17*NY)
    int ytile = pos / 17;
    int i     = xcd * 17 + (pos - ytile * 17);

    if (i >= nT[0]) return;
    int e     = tE[i];
    int goff  = tGoff[i];
    int slot0 = tSlot0[i];
    int rows  = tRows[i];
    int n0    = ytile * 256;

    const ushort_t* Ap = Aall + (size_t)goff * KTOT;
    const ushort_t* Bp = Ball + (size_t)e * KTOT * NTOT + (size_t)n0 * KTOT;

    __shared__ ushort_t As[128 * 64];      // 16 KB
    __shared__ ushort_t Bs[256 * 64];      // 32 KB
    __shared__ int   tokLds[MODE ? 128 : 1];
    __shared__ float probLds[MODE ? 128 : 1];

    int tid = threadIdx.x, lane = tid & 63, wid = tid >> 6;
    int wr = wid >> 2, wc = wid & 3;       // wave owns rows wr*64..+64, cols wc*64..+64
    int gq = lane >> 4, lm = lane & 15, l7 = lane & 7;

    if (MODE == 1 && tid < 128) {
        int tok = (tid < rows) ? perm[e * T + slot0 + tid] : 0;
        tokLds[tid]  = tok;
        probLds[tid] = (tid < rows) ? topp[tok] : 0.f;
    }

    f32x4 acc[4][4];                       // 64 regs: [mi 16-row frag][ni 16-col frag]
    const f32x4 zero = {0.f, 0.f, 0.f, 0.f};
#pragma unroll
    for (int mi = 0; mi < 4; ++mi)
#pragma unroll
        for (int ni = 0; ni < 4; ++ni) acc[mi][ni] = zero;

    const int nkt = KTOT / 64;

    for (int t = 0; t < nkt; ++t) {
        // ---- stage K-slab t: A 128x64 (2 loads/thr) + B 256x64 (4 loads/thr) ----
#pragma unroll
        for (int j = 0; j < 2; ++j) {
            int c_ = tid + j * 512;
            int rr = c_ >> 3, gg = c_ & 7;
            int srow_ = rr < rows ? rr : rows - 1;
            const ushort_t* src_ = Ap + (size_t)srow_ * KTOT + t * 64 + ((gg ^ (rr & 7)) << 3);
            __builtin_amdgcn_global_load_lds(
                (const __attribute__((address_space(1))) unsigned int*)src_,
                (__attribute__((address_space(3))) unsigned int*)&As[c_ * 8], 16, 0, 0);
        }
#pragma unroll
        for (int j = 0; j < 4; ++j) {
            int c_ = tid + j * 512;
            int rr = c_ >> 3, gg = c_ & 7;
            const ushort_t* src_ = Bp + (size_t)rr * KTOT + t * 64 + ((gg ^ (rr & 7)) << 3);
            __builtin_amdgcn_global_load_lds(
                (const __attribute__((address_space(1))) unsigned int*)src_,
                (__attribute__((address_space(3))) unsigned int*)&Bs[c_ * 8], 16, 0, 0);
        }
        asm volatile("s_waitcnt vmcnt(0)" ::: "memory");
        __builtin_amdgcn_sched_barrier(0);
        __builtin_amdgcn_s_barrier();

        // ---- compute: read B frags (8), then per-mi {read A pair, 8 MFMA} ----
        bf16x8 bb[4][2];
#pragma unroll
        for (int ni = 0; ni < 4; ++ni)
#pragma unroll
            for (int ks = 0; ks < 2; ++ks)
                bb[ni][ks] = *(const bf16x8*)&Bs[
                    (wc * 64 + ni * 16 + lm) * 64 + ((((ks << 2) + gq) ^ l7) << 3)];

        __builtin_amdgcn_s_setprio(1);
#pragma unroll
        for (int mi = 0; mi < 4; ++mi) {
            int arow = (wr * 64 + mi * 16 + lm) * 64;
            bf16x8 af0 = *(const bf16x8*)&As[arow + ((gq ^ l7) << 3)];
            bf16x8 af1 = *(const bf16x8*)&As[arow + (((4 + gq) ^ l7) << 3)];
#pragma unroll
            for (int ni = 0; ni < 4; ++ni) {
                acc[mi][ni] = __builtin_amdgcn_mfma_f32_16x16x32_bf16(af0, bb[ni][0], acc[mi][ni], 0, 0, 0);
                acc[mi][ni] = __builtin_amdgcn_mfma_f32_16x16x32_bf16(af1, bb[ni][1], acc[mi][ni], 0, 0, 0);
            }
        }
        __builtin_amdgcn_s_setprio(0);
        __builtin_amdgcn_s_barrier();      // all reads done before next stage overwrites
    }

    // ---- epilogue: C layout col = lane&15, row = (lane>>4)*4 + reg ----
    int cr = (lane >> 4) * 4;
    int cc = lane & 15;
#pragma unroll
    for (int mi = 0; mi < 4; ++mi) {
#pragma unroll
        for (int r = 0; r < 4; ++r) {
            int m = wr * 64 + mi * 16 + cr + r;
            if (m < rows) {
                if (MODE == 0) {
                    ushort_t* hp = (ushort_t*)Cout + (size_t)(goff + m) * NTOT
                                 + n0 + wc * 64 + cc;
#pragma unroll
                    for (int ni = 0; ni < 4; ++ni) {
                        float v = acc[mi][ni][r];
                        hp[ni * 16] = f2bf(v > 0.f ? v : 0.f);
                    }
                } else {
                    int tok = tokLds[m];
                    float p = probLds[m];
                    float* op = (float*)Cout + (size_t)tok * NTOT
                              + n0 + wc * 64 + cc;
#pragma unroll
                    for (int ni = 0; ni < 4; ++ni) op[ni * 16] = acc[mi][ni][r] * p;
                }
            }
        }
    }
}

// ---------------- workspace layout ----------------
constexpr size_t OFF_COUNTS  = 0;
constexpr size_t OFF_OFFSETS = 256;
constexpr size_t OFF_TILES   = 512;                                      // 5x160 ints + nT
constexpr size_t OFF_TOPP    = OFF_TILES + 3328;
constexpr size_t OFF_PERM    = OFF_TOPP + (size_t)T * 4;
constexpr size_t OFF_XG      = (OFF_PERM + (size_t)Eh * T * 4 + 255) & ~(size_t)255;
constexpr size_t OFF_H       = (OFF_XG + (size_t)(T + 128) * Dh * 2 + 255) & ~(size_t)255;
constexpr size_t OFF_WIN     = (OFF_H + (size_t)(T + 128) * Fh * 2 + 255) & ~(size_t)255;
constexpr size_t OFF_WOUT    = (OFF_WIN + (size_t)Eh * Dh * Fh * 2 + 255) & ~(size_t)255;

extern "C" void kernel_launch(void* const* d_in, const int* in_sizes, int n_in,
                              void* d_out, int out_size, void* d_ws, size_t ws_size,
                              hipStream_t stream) {
    const float* x    = (const float*)d_in[0];   // [T, Dh]
    const float* rw   = (const float*)d_in[1];   // [Dh, Eh]
    const float* w_in = (const float*)d_in[2];   // [Eh, Dh, Fh]
    const float* w_out= (const float*)d_in[3];   // [Eh, Fh, Dh]

    float* out    = (float*)d_out;               // [T, Dh]
    float* logits = out + (size_t)T * Dh;        // [T, Eh]
    float* eidx   = logits + (size_t)T * Eh;     // [T] (stored as float)

    char* ws = (char*)d_ws;
    int*      counts  = (int*)(ws + OFF_COUNTS);
    int*      offsets = (int*)(ws + OFF_OFFSETS);
    int*      L       = (int*)(ws + OFF_TILES);
    int*      tE      = L;
    int*      tGoff   = L + 160;
    int*      tSlot0  = L + 320;
    int*      tRows   = L + 480;
    int*      nT      = L + 640;
    float*    topp    = (float*)(ws + OFF_TOPP);
    int*      perm    = (int*)(ws + OFF_PERM);
    ushort_t* Xg      = (ushort_t*)(ws + OFF_XG);
    ushort_t* h       = (ushort_t*)(ws + OFF_H);
    ushort_t* WinT    = (ushort_t*)(ws + OFF_WIN);   // [E][Fh][Dh]
    ushort_t* WoutT   = (ushort_t*)(ws + OFF_WOUT);  // [E][Dh][Fh]

    hipMemsetAsync(counts, 0, Eh * sizeof(int), stream);
    router_kernel<<<T / 16, 1024, 0, stream>>>(x, rw, logits, eidx, topp, counts, perm);
    scan_counts<<<1, 64, 0, stream>>>(counts, offsets, L);
    gather_cast_x<<<(T * (Dh / 4)) / 256, 256, 0, stream>>>(x, offsets, perm, Xg);
    transpose_cvt<<<dim3(Fh / 64, Dh / 64, Eh), 256, 0, stream>>>(w_in, WinT, Dh, Fh);
    transpose_cvt<<<dim3(Dh / 64, Fh / 64, Eh), 256, 0, stream>>>(w_out, WoutT, Fh, Dh);
    moe_gemm3<Dh, Fh, 0><<<dim3(ROWT * (Fh / 256)), 512, 0, stream>>>(
        Xg, WinT, tE, tGoff, tSlot0, tRows, nT, perm, topp, (void*)h);
    moe_gemm3<Fh, Dh, 1><<<dim3(ROWT * (Dh / 256)), 512, 0, stream>>>(
        h, WoutT, tE, tGoff, tSlot0, tRows, nT, perm, topp, (void*)out);
}